// Round 5
// baseline (170.014 us; speedup 1.0000x reference)
//
#include <hip/hip_runtime.h>
#include <hip/hip_bf16.h>
#include <math.h>

#define B_     2
#define T_     2048
#define D_     1024
#define H_     16
#define INNER_ 1024
#define NC_    4352       // padded combined N: 3072 qkv + 1024 gsp + 16 dt + pad
#define SCALE_ 0.125f     // 64^-0.5, folded into Q at pointwise

typedef unsigned short u16;
typedef short short8 __attribute__((ext_vector_type(8)));
typedef float f32x4 __attribute__((ext_vector_type(4)));
typedef unsigned short u16x4 __attribute__((ext_vector_type(4)));

__device__ __forceinline__ u16 f2bf(float x) {
  union { float f; unsigned u; } v; v.f = x;
  unsigned r = v.u + 0x7fffu + ((v.u >> 16) & 1u);   // RNE, finite inputs
  return (u16)(r >> 16);
}
__device__ __forceinline__ float b2f(u16 x) {
  union { unsigned u; float f; } v; v.u = ((unsigned)x) << 16;
  return v.f;
}
// async global->LDS, 16B per lane; LDS dest = wave-uniform base + lane*16
__device__ __forceinline__ void gload16(const void* g, void* l) {
  __builtin_amdgcn_global_load_lds(
      (const __attribute__((address_space(1))) void*)g,
      (__attribute__((address_space(3))) void*)l, 16, 0, 0);
}

// ---------------------------------------------------------------------------
// prep kernels
// ---------------------------------------------------------------------------
__global__ __launch_bounds__(256) void cast_bf16_kernel(
    const float* __restrict__ src, u16* __restrict__ dst, int n4) {
  int i = blockIdx.x * 256 + threadIdx.x;
  if (i >= n4) return;
  float4 v = *reinterpret_cast<const float4*>(src + (size_t)i * 4);
  u16x4 o; o.x = f2bf(v.x); o.y = f2bf(v.y); o.z = f2bf(v.z); o.w = f2bf(v.w);
  *reinterpret_cast<u16x4*>(dst + (size_t)i * 4) = o;
}

// src [K][N] f32  ->  dst [N][K] bf16
__global__ __launch_bounds__(256) void cast_transpose_kernel(
    const float* __restrict__ src, u16* __restrict__ dst, int K, int N) {
  __shared__ float tile[64][65];
  const int k0 = blockIdx.y * 64, n0 = blockIdx.x * 64;
  for (int e = threadIdx.x; e < 4096; e += 256) {
    int kk = e >> 6, nn = e & 63;
    tile[kk][nn] = src[(size_t)(k0 + kk) * N + n0 + nn];
  }
  __syncthreads();
  for (int e = threadIdx.x; e < 4096; e += 256) {
    int nn = e >> 6, kk = e & 63;
    dst[(size_t)(n0 + nn) * K + k0 + kk] = f2bf(tile[kk][nn]);
  }
}

// W_dt [1024][16] f32 -> rows 4096..4111 of Wcombt ([h][k] bf16)
__global__ __launch_bounds__(256) void wdt_transpose_kernel(
    const float* __restrict__ W_dt, u16* __restrict__ dst) {
  int i = blockIdx.x * 256 + threadIdx.x;  // 16384
  int k = i >> 4, h = i & 15;
  dst[(size_t)h * D_ + k] = f2bf(W_dt[i]);
}

// RoPE table: tab[t*32+j] = (cos(t*invf[j]), sin(t*invf[j]))
__global__ __launch_bounds__(256) void rope_tab_kernel(
    const float* __restrict__ inv_freq, float2* __restrict__ tab) {
  int i = blockIdx.x * 256 + threadIdx.x;  // 65536
  int t = i >> 5, j = i & 31;
  float s, c;
  sincosf((float)t * inv_freq[j], &s, &c);
  tab[i] = make_float2(c, s);
}

// ---------------------------------------------------------------------------
// Big pipelined GEMM: C(4096 x 4352) = A @ Bt^T, bf16 out.
// 256x256 tile, BK=32, 8 waves (2x4), 4 LDS buffer sets (128KB), lookahead-3,
// counted vmcnt (8/4/0), one s_barrier per K-tile, setprio around MFMA.
// Swizzle: 4 16B-slots/row, phys_slot = logical ^ SWZ(row); verified 2-way max.
// ---------------------------------------------------------------------------
#define SWZG(r) ((((r) & 3) ^ (((r) >> 2) & 1)))

__device__ __forceinline__ void stage_op(const u16* __restrict__ gbase, int kt,
                                         char* ldst, int h, int tid) {
  // one call = 512 threads x 16B = 8KB = rows h*128 .. h*128+127 (64B each)
  int r = h * 128 + (tid >> 2);
  int kg = (tid & 3) ^ SWZG(r);
  gload16(gbase + (size_t)r * D_ + kt * 32 + kg * 8,
          ldst + (h * 128 + (tid >> 6) * 16) * 64);
}
__device__ __forceinline__ short8 ldfrag(const char* tile, int row, int g4) {
  return *(const short8*)(tile + row * 64 + ((g4 ^ SWZG(row)) << 4));
}

__global__ __launch_bounds__(512, 2) void gemm_big(
    const u16* __restrict__ A, const u16* __restrict__ Bt,
    u16* __restrict__ C) {
  __shared__ char lds[4 * 32768];   // [buf 4][ A 16KB | B 16KB ]
  const int tid = threadIdx.x;
  const int w = tid >> 6, l = tid & 63;
  const int bid = blockIdx.x;           // 272 blocks = 16 rows x 17 cols
  const int xcd = bid & 7, j = bid >> 3;
  const int brow = xcd * 2 + (j >= 17 ? 1 : 0);
  const int bcol = (j >= 17) ? j - 17 : j;
  const int m0 = brow * 256, n0 = bcol * 256;
  const int wr = (w >> 2) * 128, wc = (w & 3) * 64;
  const int ql = l & 15, g4 = l >> 4;

  const u16* Ag = A + (size_t)m0 * D_;
  const u16* Bg = Bt + (size_t)n0 * D_;

  f32x4 acc[8][4] = {};

  // prologue: stage K-tiles 0,1,2
#pragma unroll
  for (int t = 0; t < 3; ++t) {
    char* bufA = lds + t * 32768;
    char* bufB = bufA + 16384;
    stage_op(Ag, t, bufA, 0, tid); stage_op(Ag, t, bufA, 1, tid);
    stage_op(Bg, t, bufB, 0, tid); stage_op(Bg, t, bufB, 1, tid);
  }

  const int NT = D_ / 32;   // 32
  for (int kt = 0; kt < NT; ++kt) {
    // per-wave counted wait for K-tile kt (issued 3 tiles ago), then barrier
    // makes it collective. outstanding: kt,kt+1,kt+2 staged = 12 calls.
    if (kt < NT - 2)       asm volatile("s_waitcnt vmcnt(8)" ::: "memory");
    else if (kt == NT - 2) asm volatile("s_waitcnt vmcnt(4)" ::: "memory");
    else                   asm volatile("s_waitcnt vmcnt(0)" ::: "memory");
    __builtin_amdgcn_sched_barrier(0);
    __builtin_amdgcn_s_barrier();
    __builtin_amdgcn_sched_barrier(0);

    char* bufA = lds + (kt & 3) * 32768;
    char* bufB = bufA + 16384;
    char* nbufA = lds + ((kt + 3) & 3) * 32768;
    char* nbufB = nbufA + 16384;
    const bool pre = (kt + 3 < NT);

    // ---- phase a: stage A(kt+3) | read A m0-3 + B n0-3 | 16 MFMA
    if (pre) {
      stage_op(Ag, kt + 3, nbufA, 0, tid);
      stage_op(Ag, kt + 3, nbufA, 1, tid);
    }
    short8 bf[4];
#pragma unroll
    for (int nf = 0; nf < 4; ++nf) bf[nf] = ldfrag(bufB, wc + nf * 16 + ql, g4);
    short8 af[4];
#pragma unroll
    for (int mf = 0; mf < 4; ++mf) af[mf] = ldfrag(bufA, wr + mf * 16 + ql, g4);
    __builtin_amdgcn_s_setprio(1);
#pragma unroll
    for (int mf = 0; mf < 4; ++mf)
#pragma unroll
      for (int nf = 0; nf < 4; ++nf)
        acc[mf][nf] = __builtin_amdgcn_mfma_f32_16x16x32_bf16(af[mf], bf[nf], acc[mf][nf], 0, 0, 0);
    __builtin_amdgcn_s_setprio(0);

    // ---- phase b: stage B(kt+3) | read A m4-7 (B reused) | 16 MFMA
    if (pre) {
      stage_op(Bg, kt + 3, nbufB, 0, tid);
      stage_op(Bg, kt + 3, nbufB, 1, tid);
    }
    short8 af2[4];
#pragma unroll
    for (int mf = 0; mf < 4; ++mf) af2[mf] = ldfrag(bufA, wr + 64 + mf * 16 + ql, g4);
    __builtin_amdgcn_s_setprio(1);
#pragma unroll
    for (int mf = 0; mf < 4; ++mf)
#pragma unroll
      for (int nf = 0; nf < 4; ++nf)
        acc[mf + 4][nf] = __builtin_amdgcn_mfma_f32_16x16x32_bf16(af2[mf], bf[nf], acc[mf + 4][nf], 0, 0, 0);
    __builtin_amdgcn_s_setprio(0);
  }

  // epilogue
#pragma unroll
  for (int mf = 0; mf < 8; ++mf) {
#pragma unroll
    for (int r = 0; r < 4; ++r) {
      size_t row = (size_t)(m0 + wr + mf * 16 + g4 * 4 + r);
      size_t base = row * NC_ + n0 + wc + ql;
#pragma unroll
      for (int nf = 0; nf < 4; ++nf)
        C[base + nf * 16] = f2bf(acc[mf][nf][r]);
    }
  }
}

// ---------------------------------------------------------------------------
// bf16 MFMA GEMM (128x128, BK=64) — used for the output projection.
// ---------------------------------------------------------------------------
template <bool BF16OUT>
__global__ __launch_bounds__(256) void gemm_bt(
    const u16* __restrict__ A, const u16* __restrict__ Bt,
    void* __restrict__ Cv, int M, int N, int K) {
  __shared__ u16 As[128 * 64] __attribute__((aligned(16)));
  __shared__ u16 Bs[128 * 64] __attribute__((aligned(16)));
  const int tid = threadIdx.x;
  const int w = tid >> 6, l = tid & 63;
  const int m0 = blockIdx.y * 128, n0 = blockIdx.x * 128;
  const int wr = (w >> 1) * 64, wc = (w & 1) * 64;
  const int srow = l >> 3;
  const int kgrp = ((l & 7) ^ srow) * 8;

  f32x4 acc[4][4] = {};

  for (int kt = 0; kt < K; kt += 64) {
    if (kt) __syncthreads();
#pragma unroll
    for (int i = 0; i < 4; ++i) {
      int c = w * 4 + i;
      int row = c * 8 + srow;
      gload16(A + (size_t)(m0 + row) * K + kt + kgrp, (char*)As + c * 1024);
      gload16(Bt + (size_t)(n0 + row) * K + kt + kgrp, (char*)Bs + c * 1024);
    }
    __syncthreads();
#pragma unroll
    for (int kk = 0; kk < 2; ++kk) {
      short8 af[4], bf[4];
#pragma unroll
      for (int i = 0; i < 4; ++i) {
        int ra = wr + i * 16 + (l & 15);
        int sa = kk * 4 + (l >> 4);
        af[i] = *(const short8*)((const char*)As + ra * 128 + ((sa ^ (ra & 7)) << 4));
        int rb = wc + i * 16 + (l & 15);
        bf[i] = *(const short8*)((const char*)Bs + rb * 128 + ((sa ^ (rb & 7)) << 4));
      }
#pragma unroll
      for (int i = 0; i < 4; ++i)
#pragma unroll
        for (int j = 0; j < 4; ++j)
          acc[i][j] = __builtin_amdgcn_mfma_f32_16x16x32_bf16(af[i], bf[j], acc[i][j], 0, 0, 0);
    }
  }
#pragma unroll
  for (int i = 0; i < 4; ++i) {
#pragma unroll
    for (int r = 0; r < 4; ++r) {
      size_t row = (size_t)(m0 + wr + i * 16 + (l >> 4) * 4 + r);
      size_t base = row * N + n0 + wc + (l & 15);
#pragma unroll
      for (int j = 0; j < 4; ++j) {
        if (BF16OUT) ((u16*)Cv)[base + j * 16] = f2bf(acc[i][j][r]);
        else         ((float*)Cv)[base + j * 16] = acc[i][j][r];
      }
    }
  }
}

// ---------------------------------------------------------------------------
// streaming pointwise: C [M][NC_] = (q|k|v|praw|dt|pad). Wave per row.
// ---------------------------------------------------------------------------
__global__ __launch_bounds__(256) void pointwise_kernel(
    const u16* __restrict__ C, const float* __restrict__ b_dt,
    const float* __restrict__ b_gsp, const float2* __restrict__ tab,
    u16* __restrict__ Qb, u16* __restrict__ Kb, u16* __restrict__ Vb,
    float* __restrict__ lg) {
  const int row = blockIdx.x * 4 + (threadIdx.x >> 6);
  const int l = threadIdx.x & 63;
  const int b = row >> 11, t = row & (T_ - 1);
  const int h = l >> 2;
  const int dd0 = (l & 3) * 16;
  const int col = h * 64 + dd0;
  const size_t cb = (size_t)row * NC_;

  float dtv = b2f(C[cb + 4096 + h]) + b_dt[h];
  float sp = (dtv > 20.f) ? dtv : log1pf(__expf(dtv));
  const float gh = __expf(-sp);

  const short8* qp = (const short8*)(C + cb + col);
  const short8* kp = (const short8*)(C + cb + 1024 + col);
  const short8* vp = (const short8*)(C + cb + 2048 + col);
  const short8* pp = (const short8*)(C + cb + 3072 + col);
  short8 q0 = qp[0], q1 = qp[1];
  short8 k0 = kp[0], k1 = kp[1];
  short8 v0 = vp[0], v1 = vp[1];
  short8 pr0 = pp[0], pr1 = pp[1];

  float ge = 0.f;
  short8 vo0, vo1;
#pragma unroll
  for (int i = 0; i < 8; ++i) {
    float pv = b2f((u16)pr0[i]) + b_gsp[col + i];
    float p = 1.f / (1.f + __expf(-pv));
    ge += gh * (1.f - p) + p;
    vo0[i] = (short)f2bf(b2f((u16)v0[i]) * (1.f - p));
    float pv1 = b2f((u16)pr1[i]) + b_gsp[col + 8 + i];
    float p1 = 1.f / (1.f + __expf(-pv1));
    ge += gh * (1.f - p1) + p1;
    vo1[i] = (short)f2bf(b2f((u16)v1[i]) * (1.f - p1));
  }
  const size_t hm = (((size_t)(b * H_ + h)) * T_ + t) * 64 + dd0;
  ((short8*)(Vb + hm))[0] = vo0;
  ((short8*)(Vb + hm))[1] = vo1;

  ge += __shfl_xor(ge, 1);
  ge += __shfl_xor(ge, 2);
  if ((l & 3) == 0) {
    float gs = ge * (1.f / 64.f);
    gs = fminf(fmaxf(gs, 1e-6f), 1.f - 1e-6f);
    lg[((size_t)(b * H_ + h)) * T_ + t] = logf(gs);
  }

  short8 qo0, qo1, ko0, ko1;
  const float2* cs = tab + t * 32 + (dd0 >> 1);
#pragma unroll
  for (int m = 0; m < 4; ++m) {
    float2 c0 = cs[m];
    float qa = b2f((u16)q0[2 * m]), qb = b2f((u16)q0[2 * m + 1]);
    qo0[2 * m]     = (short)f2bf((qa * c0.x - qb * c0.y) * SCALE_);
    qo0[2 * m + 1] = (short)f2bf((qa * c0.y + qb * c0.x) * SCALE_);
    float ka = b2f((u16)k0[2 * m]), kb = b2f((u16)k0[2 * m + 1]);
    ko0[2 * m]     = (short)f2bf(ka * c0.x - kb * c0.y);
    ko0[2 * m + 1] = (short)f2bf(ka * c0.y + kb * c0.x);
    float2 c1 = cs[4 + m];
    float qa1 = b2f((u16)q1[2 * m]), qb1 = b2f((u16)q1[2 * m + 1]);
    qo1[2 * m]     = (short)f2bf((qa1 * c1.x - qb1 * c1.y) * SCALE_);
    qo1[2 * m + 1] = (short)f2bf((qa1 * c1.y + qb1 * c1.x) * SCALE_);
    float ka1 = b2f((u16)k1[2 * m]), kb1 = b2f((u16)k1[2 * m + 1]);
    ko1[2 * m]     = (short)f2bf(ka1 * c1.x - kb1 * c1.y);
    ko1[2 * m + 1] = (short)f2bf(ka1 * c1.y + kb1 * c1.x);
  }
  ((short8*)(Qb + hm))[0] = qo0; ((short8*)(Qb + hm))[1] = qo1;
  ((short8*)(Kb + hm))[0] = ko0; ((short8*)(Kb + hm))[1] = ko1;
}

// ---------------------------------------------------------------------------
// inclusive cumsum over T per (b,h)
// ---------------------------------------------------------------------------
__global__ __launch_bounds__(256) void scan_kernel(
    const float* __restrict__ lg, float* __restrict__ lgc) {
  const size_t base = (size_t)blockIdx.x * T_;
  const int tid = threadIdx.x;
  __shared__ float sums[256];
  float loc[8];
  float run = 0.f;
#pragma unroll
  for (int i = 0; i < 8; ++i) { run += lg[base + tid * 8 + i]; loc[i] = run; }
  sums[tid] = run;
  __syncthreads();
  if (tid == 0) {
    float r = 0.f;
    for (int i = 0; i < 256; ++i) { float v = sums[i]; sums[i] = r; r += v; }
  }
  __syncthreads();
  const float off = sums[tid];
#pragma unroll
  for (int i = 0; i < 8; ++i) lgc[base + tid * 8 + i] = off + loc[i];
}

// ---------------------------------------------------------------------------
// kv_prep: K' = K * beta[s]; Vtg[bh][dd][t] = V[bh][t][dd]
// ---------------------------------------------------------------------------
__global__ __launch_bounds__(256) void kv_prep_kernel(
    const u16* __restrict__ Kb, const u16* __restrict__ Vb,
    const float* __restrict__ lgc, u16* __restrict__ Kp,
    u16* __restrict__ Vtg) {
  const int stile = blockIdx.x;
  const int bh = blockIdx.y;
  const int tid = threadIdx.x;
  __shared__ u16 vt[64][72];
  const size_t base = ((size_t)bh * T_ + (size_t)stile * 64) * 64;
  const float* lgp = lgc + (size_t)bh * T_;
  const float lgb = lgp[stile * 64];
#pragma unroll
  for (int i = 0; i < 2; ++i) {
    int c = tid * 2 + i;
    int row = c >> 3, k8 = (c & 7) * 8;
    float beta = __expf(lgb - lgp[stile * 64 + row]);
    short8 kv = *(const short8*)(Kb + base + row * 64 + k8);
    short8 ko;
#pragma unroll
    for (int j = 0; j < 8; ++j) ko[j] = (short)f2bf(b2f((u16)kv[j]) * beta);
    *(short8*)(Kp + base + row * 64 + k8) = ko;
    short8 vv = *(const short8*)(Vb + base + row * 64 + k8);
#pragma unroll
    for (int j = 0; j < 8; ++j) vt[row][k8 + j] = (u16)vv[j];
  }
  __syncthreads();
#pragma unroll
  for (int i = 0; i < 2; ++i) {
    int c = tid * 2 + i;
    int dd = c >> 3, t8 = (c & 7) * 8;
    short8 o;
#pragma unroll
    for (int j = 0; j < 8; ++j) o[j] = (short)vt[t8 + j][dd];
    *(short8*)(Vtg + ((size_t)bh * 64 + dd) * T_ + stile * 64 + t8) = o;
  }
}

// ---------------------------------------------------------------------------
// MFMA attention, decay-factorized, XCD-swizzled.
// ---------------------------------------------------------------------------
__global__ __launch_bounds__(256) void attn_mfma(
    const u16* __restrict__ Qb, const u16* __restrict__ Kp,
    const u16* __restrict__ Vtg, const float* __restrict__ lgc,
    u16* __restrict__ Y) {
  const int i = blockIdx.x;
  const int tt = (i >> 3) & 31;
  const int bh = (i & 7) + ((i >> 8) << 3);
  const int b = bh >> 4, h = bh & 15;
  const int tid = threadIdx.x, w = tid >> 6, l = tid & 63;
  __shared__ u16 Qs[64 * 64] __attribute__((aligned(16)));   // reused as P
  __shared__ u16 Ks[64 * 64] __attribute__((aligned(16)));
  __shared__ u16 Vs[64 * 64] __attribute__((aligned(16)));
  const u16* Qg = Qb + (size_t)bh * T_ * 64;
  const u16* Kg = Kp + (size_t)bh * T_ * 64;
  const u16* Vg = Vtg + (size_t)bh * 64 * T_;
  const float* lgp = lgc + (size_t)bh * T_;

  const int srow = l >> 3;
  const int kgrp = ((l & 7) ^ srow) * 8;
  const int ql = l & 15, g4 = l >> 4;

#pragma unroll
  for (int i2 = 0; i2 < 2; ++i2) {
    int c = w * 2 + i2;
    int row = c * 8 + srow;
    gload16(Qg + (size_t)(tt * 64 + row) * 64 + kgrp, (char*)Qs + c * 1024);
  }
  const float lgq = lgp[tt * 64 + w * 16 + ql];
  const float lgtop = lgp[tt * 64];
  __syncthreads();

  short8 qf[2];
#pragma unroll
  for (int kk = 0; kk < 2; ++kk) {
    int row = w * 16 + ql;
    int slot = kk * 4 + g4;
    qf[kk] = *(const short8*)((const char*)Qs + row * 128 + ((slot ^ (row & 7)) << 4));
  }
  char* Pw = (char*)Qs + w * 2048;
  const int pswz = (ql & 7) << 4;

  f32x4 yacc[4] = {};

  for (int st = tt; st >= 0; --st) {
    if (st < tt && lgtop - lgp[st * 64 + 63] <= -20.f) break;
    __syncthreads();
#pragma unroll
    for (int i2 = 0; i2 < 2; ++i2) {
      int c = w * 2 + i2;
      int row = c * 8 + srow;
      gload16(Kg + (size_t)(st * 64 + row) * 64 + kgrp, (char*)Ks + c * 1024);
      gload16(Vg + (size_t)row * T_ + st * 64 + kgrp, (char*)Vs + c * 1024);
    }
    const float alpha = __expf(lgq - lgp[st * 64]);
    __syncthreads();

    const bool diag = (st == tt);
#pragma unroll
    for (int n = 0; n < 4; ++n) {
      f32x4 s = {};
#pragma unroll
      for (int kk = 0; kk < 2; ++kk) {
        int row = n * 16 + ql;
        int slot = kk * 4 + g4;
        short8 kf = *(const short8*)((const char*)Ks + row * 128 + ((slot ^ (row & 7)) << 4));
        s = __builtin_amdgcn_mfma_f32_16x16x32_bf16(kf, qf[kk], s, 0, 0, 0);
      }
      u16x4 pk;
#pragma unroll
      for (int r = 0; r < 4; ++r) {
        float pv = s[r] * alpha;
        if (diag && (n * 16 + g4 * 4 + r) > (w * 16 + ql)) pv = 0.f;
        pk[r] = f2bf(pv);
      }
      *(u16x4*)(Pw + ((ql * 128 + n * 32 + g4 * 8) ^ pswz)) = pk;
    }
#pragma unroll
    for (int kk = 0; kk < 2; ++kk) {
      short8 pf = *(const short8*)(Pw + ((ql * 128 + kk * 64 + g4 * 16) ^ pswz));
#pragma unroll
      for (int n2 = 0; n2 < 4; ++n2) {
        int row = n2 * 16 + ql;
        int slot = kk * 4 + g4;
        short8 vf = *(const short8*)((const char*)Vs + row * 128 + ((slot ^ (row & 7)) << 4));
        yacc[n2] = __builtin_amdgcn_mfma_f32_16x16x32_bf16(pf, vf, yacc[n2], 0, 0, 0);
      }
    }
  }

#pragma unroll
  for (int n2 = 0; n2 < 4; ++n2)
#pragma unroll
    for (int r = 0; r < 4; ++r) {
      size_t row = (size_t)(b * T_) + tt * 64 + w * 16 + g4 * 4 + r;
      Y[row * INNER_ + h * 64 + n2 * 16 + ql] = f2bf(yacc[n2][r]);
    }
}

// ---------------------------------------------------------------------------
extern "C" void kernel_launch(void* const* d_in, const int* in_sizes, int n_in,
                              void* d_out, int out_size, void* d_ws, size_t ws_size,
                              hipStream_t stream) {
  const float* x        = (const float*)d_in[0];
  const float* W_qkv    = (const float*)d_in[1];
  const float* W_out    = (const float*)d_in[2];
  const float* W_dt     = (const float*)d_in[3];
  const float* b_dt     = (const float*)d_in[4];
  const float* W_gsp    = (const float*)d_in[5];
  const float* b_gsp    = (const float*)d_in[6];
  const float* inv_freq = (const float*)d_in[7];
  float* out = (float*)d_out;

  const int M = B_ * T_;  // 4096
  char* p = (char*)d_ws;
  auto alloc = [&](size_t bytes) {
    char* r = p; p += (bytes + 255) & ~(size_t)255; return r;
  };
  u16*    xb    = (u16*)alloc((size_t)M * D_ * 2);             // 8 MB
  u16*    Wcombt= (u16*)alloc((size_t)NC_ * D_ * 2);           // 8.9 MB
  u16*    Woutt = (u16*)alloc((size_t)D_ * INNER_ * 2);        // 2 MB
  u16*    Cqkvp = (u16*)alloc((size_t)M * NC_ * 2);            // 35.7 MB
  u16*    Qb    = (u16*)alloc((size_t)B_ * H_ * T_ * 64 * 2);  // 8 MB
  u16*    Kb    = (u16*)alloc((size_t)B_ * H_ * T_ * 64 * 2);
  u16*    Vb    = (u16*)alloc((size_t)B_ * H_ * T_ * 64 * 2);
  float*  lg    = (float*)alloc((size_t)B_ * H_ * T_ * 4);
  float*  lgc   = (float*)alloc((size_t)B_ * H_ * T_ * 4);
  float2* tab   = (float2*)alloc((size_t)T_ * 32 * 8);         // 512 KB
  // after pointwise, Cqkvp is dead -> alias attention buffers into it
  u16*    Kp    = Cqkvp;                                       // 8 MB
  u16*    Vtg   = Cqkvp + (size_t)4 * 1024 * 1024;             // 8 MB
  u16*    Yb    = Cqkvp + (size_t)8 * 1024 * 1024;             // 8 MB

  // prep
  cast_bf16_kernel<<<(M * D_ / 4 + 255) / 256, 256, 0, stream>>>(x, xb, M * D_ / 4);
  rope_tab_kernel<<<T_ * 32 / 256, 256, 0, stream>>>(inv_freq, tab);
  cast_transpose_kernel<<<dim3(3 * INNER_ / 64, D_ / 64), 256, 0, stream>>>(
      W_qkv, Wcombt, D_, 3 * INNER_);
  cast_transpose_kernel<<<dim3(INNER_ / 64, D_ / 64), 256, 0, stream>>>(
      W_gsp, Wcombt + (size_t)3 * INNER_ * D_, D_, INNER_);
  wdt_transpose_kernel<<<64, 256, 0, stream>>>(W_dt, Wcombt + (size_t)4096 * D_);
  cast_transpose_kernel<<<dim3(D_ / 64, INNER_ / 64), 256, 0, stream>>>(
      W_out, Woutt, INNER_, D_);

  // combined projection GEMM: [q|k|v|praw|dt] = x @ Wcomb (256^2 pipelined)
  gemm_big<<<272, 512, 0, stream>>>(xb, Wcombt, Cqkvp);

  pointwise_kernel<<<M / 4, 256, 0, stream>>>(Cqkvp, b_dt, b_gsp, tab,
                                              Qb, Kb, Vb, lg);
  scan_kernel<<<B_ * H_, 256, 0, stream>>>(lg, lgc);
  kv_prep_kernel<<<dim3(T_ / 64, B_ * H_), 256, 0, stream>>>(Kb, Vb, lgc, Kp, Vtg);

  attn_mfma<<<1024, 256, 0, stream>>>(Qb, Kp, Vtg, lgc, Yb);

  // out = Y @ W_out  (fp32 out)
  gemm_bt<false><<<dim3(D_ / 128, M / 128), 256, 0, stream>>>(
      Yb, Woutt, out, M, D_, INNER_);
}

// Round 6
// 156.185 us; speedup vs baseline: 1.0885x; 1.0885x over previous
//
#include <hip/hip_runtime.h>
#include <hip/hip_bf16.h>
#include <math.h>

#define B_     2
#define T_     2048
#define D_     1024
#define H_     16
#define INNER_ 1024
#define NC_    4096       // combined GEMM N: 3072 qkv + 1024 gsp
#define SCALE_ 0.125f     // 64^-0.5, folded into Q at pointwise

typedef unsigned short u16;
typedef short short8 __attribute__((ext_vector_type(8)));
typedef float f32x4 __attribute__((ext_vector_type(4)));
typedef unsigned short u16x4 __attribute__((ext_vector_type(4)));

__device__ __forceinline__ u16 f2bf(float x) {
  union { float f; unsigned u; } v; v.f = x;
  unsigned r = v.u + 0x7fffu + ((v.u >> 16) & 1u);   // RNE, finite inputs
  return (u16)(r >> 16);
}
__device__ __forceinline__ float b2f(u16 x) {
  union { unsigned u; float f; } v; v.u = ((unsigned)x) << 16;
  return v.f;
}
// async global->LDS, 16B per lane; LDS dest = wave-uniform base + lane*16
__device__ __forceinline__ void gload16(const void* g, void* l) {
  __builtin_amdgcn_global_load_lds(
      (const __attribute__((address_space(1))) void*)g,
      (__attribute__((address_space(3))) void*)l, 16, 0, 0);
}

// ---------------------------------------------------------------------------
// fused prep: [0,1280) weight transposes | [1280,1344) wdt | [1344,1600) rope
// | [1600,2624) cast x.  All branches block-uniform.
// ---------------------------------------------------------------------------
__global__ __launch_bounds__(256) void prep_kernel(
    const float* __restrict__ x, const float* __restrict__ W_qkv,
    const float* __restrict__ W_gsp, const float* __restrict__ W_out,
    const float* __restrict__ W_dt, const float* __restrict__ inv_freq,
    u16* __restrict__ xb, u16* __restrict__ Wcombt, u16* __restrict__ Woutt,
    u16* __restrict__ Wdtb, float2* __restrict__ tab) {
  const int bid = blockIdx.x, tid = threadIdx.x;
  if (bid < 1280) {   // 64x64 cast-transpose tiles, K=1024
    const float* src; u16* dst; int N, nx, ky;
    if (bid < 768)       { src = W_qkv; dst = Wcombt;                N = 3072; nx = bid % 48;          ky = bid / 48; }
    else if (bid < 1024) { src = W_gsp; dst = Wcombt + 3072 * 1024;  N = 1024; nx = (bid - 768) % 16;  ky = (bid - 768) / 16; }
    else                 { src = W_out; dst = Woutt;                 N = 1024; nx = (bid - 1024) % 16; ky = (bid - 1024) / 16; }
    __shared__ float tile[64][65];
    const int k0 = ky * 64, n0 = nx * 64;
    for (int e = tid; e < 4096; e += 256) {
      int kk = e >> 6, nn = e & 63;
      tile[kk][nn] = src[(size_t)(k0 + kk) * N + n0 + nn];
    }
    __syncthreads();
    for (int e = tid; e < 4096; e += 256) {
      int nn = e >> 6, kk = e & 63;
      dst[(size_t)(n0 + nn) * 1024 + k0 + kk] = f2bf(tile[kk][nn]);
    }
  } else if (bid < 1344) {   // W_dt [1024][16] -> Wdtb [16][1024]
    int i = (bid - 1280) * 256 + tid;
    int k = i >> 4, h = i & 15;
    Wdtb[(size_t)h * D_ + k] = f2bf(W_dt[i]);
  } else if (bid < 1600) {   // rope table
    int i = (bid - 1344) * 256 + tid;
    int t = i >> 5, j = i & 31;
    float s, c;
    sincosf((float)t * inv_freq[j], &s, &c);
    tab[i] = make_float2(c, s);
  } else {                   // cast x -> bf16, 4 float4 per thread
    int base = (bid - 1600) * 1024 + tid;
#pragma unroll
    for (int r = 0; r < 4; ++r) {
      int i = base + r * 256;
      float4 v = *reinterpret_cast<const float4*>(x + (size_t)i * 4);
      u16x4 o; o.x = f2bf(v.x); o.y = f2bf(v.y); o.z = f2bf(v.z); o.w = f2bf(v.w);
      *reinterpret_cast<u16x4*>(xb + (size_t)i * 4) = o;
    }
  }
}

// ---------------------------------------------------------------------------
// gamma: gam[row][h] = exp(-softplus(x_row . W_dt[:,h] + b_dt[h]))
// wave per row; 4 lanes per head x 256 k-elems.
// ---------------------------------------------------------------------------
__global__ __launch_bounds__(256) void gamma_kernel(
    const u16* __restrict__ xb, const u16* __restrict__ Wdtb,
    const float* __restrict__ b_dt, float* __restrict__ gam) {
  const int row = blockIdx.x * 4 + (threadIdx.x >> 6);
  const int l = threadIdx.x & 63;
  const int h = l >> 2;
  const int kc = (l & 3) * 256;
  const short8* xp = (const short8*)(xb + (size_t)row * D_ + kc);
  const short8* wp = (const short8*)(Wdtb + h * D_ + kc);
  float s = 0.f;
#pragma unroll
  for (int i = 0; i < 32; ++i) {
    short8 xv = xp[i], wv = wp[i];
#pragma unroll
    for (int j = 0; j < 8; ++j) s += b2f((u16)xv[j]) * b2f((u16)wv[j]);
  }
  s += __shfl_xor(s, 1);
  s += __shfl_xor(s, 2);
  if ((l & 3) == 0) {
    float v = s + b_dt[h];
    float sp = (v > 20.f) ? v : log1pf(__expf(v));
    gam[row * H_ + h] = __expf(-sp);
  }
}

// ---------------------------------------------------------------------------
// Big pipelined GEMM: C(4096 x 4096) = A @ Bt^T, bf16 out. 256x256 tile,
// BK=32, 8 waves, 4 LDS buffers (128KB), lookahead-3, counted vmcnt,
// one barrier per K-tile. Grid = 256 = exactly 1 block/CU; XCD regions 4x8.
// ---------------------------------------------------------------------------
#define SWZG(r) ((((r) & 3) ^ (((r) >> 2) & 1)))

__device__ __forceinline__ void stage_op(const u16* __restrict__ gbase, int kt,
                                         char* ldst, int h, int tid) {
  int r = h * 128 + (tid >> 2);
  int kg = (tid & 3) ^ SWZG(r);
  gload16(gbase + (size_t)r * D_ + kt * 32 + kg * 8,
          ldst + (h * 128 + (tid >> 6) * 16) * 64);
}
__device__ __forceinline__ short8 ldfrag(const char* tile, int row, int g4) {
  return *(const short8*)(tile + row * 64 + ((g4 ^ SWZG(row)) << 4));
}

__global__ __launch_bounds__(512, 2) void gemm_big(
    const u16* __restrict__ A, const u16* __restrict__ Bt,
    u16* __restrict__ C) {
  __shared__ char lds[4 * 32768];   // [buf 4][ A 16KB | B 16KB ]
  const int tid = threadIdx.x;
  const int w = tid >> 6, l = tid & 63;
  const int bid = blockIdx.x;               // 256 blocks = 16 x 16 tiles
  const int xcd = bid & 7, idx = bid >> 3;  // idx 0..31
  const int brow = (xcd >> 1) * 4 + (idx & 3);
  const int bcol = (xcd & 1) * 8 + (idx >> 2);
  const int m0 = brow * 256, n0 = bcol * 256;
  const int wr = (w >> 2) * 128, wc = (w & 3) * 64;
  const int ql = l & 15, g4 = l >> 4;

  const u16* Ag = A + (size_t)m0 * D_;
  const u16* Bg = Bt + (size_t)n0 * D_;

  f32x4 acc[8][4] = {};

#pragma unroll
  for (int t = 0; t < 3; ++t) {   // prologue: stage tiles 0..2
    char* bufA = lds + t * 32768;
    char* bufB = bufA + 16384;
    stage_op(Ag, t, bufA, 0, tid); stage_op(Ag, t, bufA, 1, tid);
    stage_op(Bg, t, bufB, 0, tid); stage_op(Bg, t, bufB, 1, tid);
  }

  const int NT = D_ / 32;   // 32
  for (int kt = 0; kt < NT; ++kt) {
    if (kt < NT - 2)       asm volatile("s_waitcnt vmcnt(8)" ::: "memory");
    else if (kt == NT - 2) asm volatile("s_waitcnt vmcnt(4)" ::: "memory");
    else                   asm volatile("s_waitcnt vmcnt(0)" ::: "memory");
    __builtin_amdgcn_sched_barrier(0);
    __builtin_amdgcn_s_barrier();
    __builtin_amdgcn_sched_barrier(0);

    char* bufA = lds + (kt & 3) * 32768;
    char* bufB = bufA + 16384;
    char* nbufA = lds + ((kt + 3) & 3) * 32768;
    char* nbufB = nbufA + 16384;
    const bool pre = (kt + 3 < NT);

    if (pre) {
      stage_op(Ag, kt + 3, nbufA, 0, tid);
      stage_op(Ag, kt + 3, nbufA, 1, tid);
    }
    short8 bf[4];
#pragma unroll
    for (int nf = 0; nf < 4; ++nf) bf[nf] = ldfrag(bufB, wc + nf * 16 + ql, g4);
    short8 af[4];
#pragma unroll
    for (int mf = 0; mf < 4; ++mf) af[mf] = ldfrag(bufA, wr + mf * 16 + ql, g4);
    __builtin_amdgcn_s_setprio(1);
#pragma unroll
    for (int mf = 0; mf < 4; ++mf)
#pragma unroll
      for (int nf = 0; nf < 4; ++nf)
        acc[mf][nf] = __builtin_amdgcn_mfma_f32_16x16x32_bf16(af[mf], bf[nf], acc[mf][nf], 0, 0, 0);
    __builtin_amdgcn_s_setprio(0);

    if (pre) {
      stage_op(Bg, kt + 3, nbufB, 0, tid);
      stage_op(Bg, kt + 3, nbufB, 1, tid);
    }
    short8 af2[4];
#pragma unroll
    for (int mf = 0; mf < 4; ++mf) af2[mf] = ldfrag(bufA, wr + 64 + mf * 16 + ql, g4);
    __builtin_amdgcn_s_setprio(1);
#pragma unroll
    for (int mf = 0; mf < 4; ++mf)
#pragma unroll
      for (int nf = 0; nf < 4; ++nf)
        acc[mf + 4][nf] = __builtin_amdgcn_mfma_f32_16x16x32_bf16(af2[mf], bf[nf], acc[mf + 4][nf], 0, 0, 0);
    __builtin_amdgcn_s_setprio(0);
  }

#pragma unroll
  for (int mf = 0; mf < 8; ++mf) {
#pragma unroll
    for (int r = 0; r < 4; ++r) {
      size_t row = (size_t)(m0 + wr + mf * 16 + g4 * 4 + r);
      size_t base = row * NC_ + n0 + wc + ql;
#pragma unroll
      for (int nf = 0; nf < 4; ++nf)
        C[base + nf * 16] = f2bf(acc[mf][nf][r]);
    }
  }
}

// ---------------------------------------------------------------------------
// 128x128 GEMM (out-proj): dbuf + counted vmcnt, 1D grid w/ XCD row-bands.
// ---------------------------------------------------------------------------
template <bool BF16OUT>
__global__ __launch_bounds__(256) void gemm_bt(
    const u16* __restrict__ A, const u16* __restrict__ Bt,
    void* __restrict__ Cv, int M, int N, int K) {
  __shared__ u16 As[2][128 * 64] __attribute__((aligned(16)));
  __shared__ u16 Bs[2][128 * 64] __attribute__((aligned(16)));
  const int tid = threadIdx.x, w = tid >> 6, l = tid & 63;
  const int rpx = (M >> 7) >> 3;            // rows per XCD (M=4096 -> 4)
  const int bid = blockIdx.x;
  const int xcd = bid & 7, idx = bid >> 3;
  const int brow = xcd * rpx + (idx % rpx);
  const int bcol = idx / rpx;
  const int m0 = brow * 128, n0 = bcol * 128;
  const int wr = (w >> 1) * 64, wc = (w & 1) * 64;
  const int srow = l >> 3;
  const int kgrp = ((l & 7) ^ srow) * 8;

  f32x4 acc[4][4] = {};

  auto stage = [&](int kt, int bs) {
#pragma unroll
    for (int i = 0; i < 4; ++i) {
      int c = w * 4 + i;
      int row = c * 8 + srow;
      gload16(A + (size_t)(m0 + row) * K + kt * 64 + kgrp, (char*)As[bs] + c * 1024);
      gload16(Bt + (size_t)(n0 + row) * K + kt * 64 + kgrp, (char*)Bs[bs] + c * 1024);
    }
  };

  stage(0, 0);
  const int NT = K >> 6;
  for (int kt = 0; kt < NT; ++kt) {
    if (kt + 1 < NT) {
      stage(kt + 1, (kt + 1) & 1);
      asm volatile("s_waitcnt vmcnt(8)" ::: "memory");
    } else {
      asm volatile("s_waitcnt vmcnt(0)" ::: "memory");
    }
    __builtin_amdgcn_sched_barrier(0);
    __builtin_amdgcn_s_barrier();
    __builtin_amdgcn_sched_barrier(0);
    const char* Asb = (const char*)As[kt & 1];
    const char* Bsb = (const char*)Bs[kt & 1];
#pragma unroll
    for (int kk = 0; kk < 2; ++kk) {
      short8 af[4], bf[4];
#pragma unroll
      for (int i = 0; i < 4; ++i) {
        int ra = wr + i * 16 + (l & 15);
        int sa = kk * 4 + (l >> 4);
        af[i] = *(const short8*)(Asb + ra * 128 + ((sa ^ (ra & 7)) << 4));
        int rb = wc + i * 16 + (l & 15);
        bf[i] = *(const short8*)(Bsb + rb * 128 + ((sa ^ (rb & 7)) << 4));
      }
#pragma unroll
      for (int i = 0; i < 4; ++i)
#pragma unroll
        for (int j = 0; j < 4; ++j)
          acc[i][j] = __builtin_amdgcn_mfma_f32_16x16x32_bf16(af[i], bf[j], acc[i][j], 0, 0, 0);
    }
    if (kt + 1 < NT) __builtin_amdgcn_s_barrier();   // protect buf (kt&1)^... next stage target
  }
#pragma unroll
  for (int i = 0; i < 4; ++i) {
#pragma unroll
    for (int r = 0; r < 4; ++r) {
      size_t row = (size_t)(m0 + wr + i * 16 + (l >> 4) * 4 + r);
      size_t base = row * N + n0 + wc + (l & 15);
#pragma unroll
      for (int j = 0; j < 4; ++j) {
        if (BF16OUT) ((u16*)Cv)[base + j * 16] = f2bf(acc[i][j][r]);
        else         ((float*)Cv)[base + j * 16] = acc[i][j][r];
      }
    }
  }
}

// ---------------------------------------------------------------------------
// streaming pointwise: C [M][4096] = (q|k|v|praw). Wave per row.
// ---------------------------------------------------------------------------
__global__ __launch_bounds__(256) void pointwise_kernel(
    const u16* __restrict__ C, const float* __restrict__ gam,
    const float* __restrict__ b_gsp, const float2* __restrict__ tab,
    u16* __restrict__ Qb, u16* __restrict__ Kb, u16* __restrict__ Vb,
    float* __restrict__ lg) {
  const int row = blockIdx.x * 4 + (threadIdx.x >> 6);
  const int l = threadIdx.x & 63;
  const int b = row >> 11, t = row & (T_ - 1);
  const int h = l >> 2;
  const int dd0 = (l & 3) * 16;
  const int col = h * 64 + dd0;
  const size_t cb = (size_t)row * NC_;

  const float gh = gam[row * H_ + h];
  const short8* qp = (const short8*)(C + cb + col);
  const short8* kp = (const short8*)(C + cb + 1024 + col);
  const short8* vp = (const short8*)(C + cb + 2048 + col);
  const short8* pp = (const short8*)(C + cb + 3072 + col);
  short8 q0 = qp[0], q1 = qp[1];
  short8 k0 = kp[0], k1 = kp[1];
  short8 v0 = vp[0], v1 = vp[1];
  short8 pr0 = pp[0], pr1 = pp[1];

  float ge = 0.f;
  short8 vo0, vo1;
#pragma unroll
  for (int i = 0; i < 8; ++i) {
    float pv = b2f((u16)pr0[i]) + b_gsp[col + i];
    float p = 1.f / (1.f + __expf(-pv));
    ge += gh * (1.f - p) + p;
    vo0[i] = (short)f2bf(b2f((u16)v0[i]) * (1.f - p));
    float pv1 = b2f((u16)pr1[i]) + b_gsp[col + 8 + i];
    float p1 = 1.f / (1.f + __expf(-pv1));
    ge += gh * (1.f - p1) + p1;
    vo1[i] = (short)f2bf(b2f((u16)v1[i]) * (1.f - p1));
  }
  const size_t hm = (((size_t)(b * H_ + h)) * T_ + t) * 64 + dd0;
  ((short8*)(Vb + hm))[0] = vo0;
  ((short8*)(Vb + hm))[1] = vo1;

  ge += __shfl_xor(ge, 1);
  ge += __shfl_xor(ge, 2);
  if ((l & 3) == 0) {
    float gs = ge * (1.f / 64.f);
    gs = fminf(fmaxf(gs, 1e-6f), 1.f - 1e-6f);
    lg[((size_t)(b * H_ + h)) * T_ + t] = logf(gs);
  }

  short8 qo0, qo1, ko0, ko1;
  const float2* cs = tab + t * 32 + (dd0 >> 1);
#pragma unroll
  for (int m = 0; m < 4; ++m) {
    float2 c0 = cs[m];
    float qa = b2f((u16)q0[2 * m]), qb = b2f((u16)q0[2 * m + 1]);
    qo0[2 * m]     = (short)f2bf((qa * c0.x - qb * c0.y) * SCALE_);
    qo0[2 * m + 1] = (short)f2bf((qa * c0.y + qb * c0.x) * SCALE_);
    float ka = b2f((u16)k0[2 * m]), kb = b2f((u16)k0[2 * m + 1]);
    ko0[2 * m]     = (short)f2bf(ka * c0.x - kb * c0.y);
    ko0[2 * m + 1] = (short)f2bf(ka * c0.y + kb * c0.x);
    float2 c1 = cs[4 + m];
    float qa1 = b2f((u16)q1[2 * m]), qb1 = b2f((u16)q1[2 * m + 1]);
    qo1[2 * m]     = (short)f2bf((qa1 * c1.x - qb1 * c1.y) * SCALE_);
    qo1[2 * m + 1] = (short)f2bf((qa1 * c1.y + qb1 * c1.x) * SCALE_);
    float ka1 = b2f((u16)k1[2 * m]), kb1 = b2f((u16)k1[2 * m + 1]);
    ko1[2 * m]     = (short)f2bf(ka1 * c1.x - kb1 * c1.y);
    ko1[2 * m + 1] = (short)f2bf(ka1 * c1.y + kb1 * c1.x);
  }
  ((short8*)(Qb + hm))[0] = qo0; ((short8*)(Qb + hm))[1] = qo1;
  ((short8*)(Kb + hm))[0] = ko0; ((short8*)(Kb + hm))[1] = ko1;
}

// ---------------------------------------------------------------------------
// inclusive cumsum over T per (b,h)
// ---------------------------------------------------------------------------
__global__ __launch_bounds__(256) void scan_kernel(
    const float* __restrict__ lg, float* __restrict__ lgc) {
  const size_t base = (size_t)blockIdx.x * T_;
  const int tid = threadIdx.x;
  __shared__ float sums[256];
  float loc[8];
  float run = 0.f;
#pragma unroll
  for (int i = 0; i < 8; ++i) { run += lg[base + tid * 8 + i]; loc[i] = run; }
  sums[tid] = run;
  __syncthreads();
  if (tid == 0) {
    float r = 0.f;
    for (int i = 0; i < 256; ++i) { float v = sums[i]; sums[i] = r; r += v; }
  }
  __syncthreads();
  const float off = sums[tid];
#pragma unroll
  for (int i = 0; i < 8; ++i) lgc[base + tid * 8 + i] = off + loc[i];
}

// ---------------------------------------------------------------------------
// kv_prep: Vtg[bh][dd][t] = V[bh][t][dd] * beta, beta = exp(lgc[base]-lgc[t])
// (beta folded into V: P·(beta V) == (beta K)·Q path, same algebra)
// ---------------------------------------------------------------------------
__global__ __launch_bounds__(256) void kv_prep_kernel(
    const u16* __restrict__ Vb, const float* __restrict__ lgc,
    u16* __restrict__ Vtg) {
  const int stile = blockIdx.x;
  const int bh = blockIdx.y;
  const int tid = threadIdx.x;
  __shared__ u16 vt[64][72];
  const size_t base = ((size_t)bh * T_ + (size_t)stile * 64) * 64;
  const float* lgp = lgc + (size_t)bh * T_;
  const float lgb = lgp[stile * 64];
#pragma unroll
  for (int i = 0; i < 2; ++i) {
    int c = tid * 2 + i;
    int row = c >> 3, k8 = (c & 7) * 8;
    float beta = __expf(lgb - lgp[stile * 64 + row]);
    short8 vv = *(const short8*)(Vb + base + row * 64 + k8);
#pragma unroll
    for (int j = 0; j < 8; ++j) vt[row][k8 + j] = f2bf(b2f((u16)vv[j]) * beta);
  }
  __syncthreads();
#pragma unroll
  for (int i = 0; i < 2; ++i) {
    int c = tid * 2 + i;
    int dd = c >> 3, t8 = (c & 7) * 8;
    short8 o;
#pragma unroll
    for (int j = 0; j < 8; ++j) o[j] = (short)vt[t8 + j][dd];
    *(short8*)(Vtg + ((size_t)bh * 64 + dd) * T_ + stile * 64 + t8) = o;
  }
}

// ---------------------------------------------------------------------------
// MFMA attention, decay-factorized, XCD-swizzled, K/V double-buffered with
// counted vmcnt (2 raw barriers/tile, loads in flight across barriers).
// ---------------------------------------------------------------------------
__global__ __launch_bounds__(256) void attn_mfma(
    const u16* __restrict__ Qb, const u16* __restrict__ Kb,
    const u16* __restrict__ Vtg, const float* __restrict__ lgc,
    u16* __restrict__ Y) {
  const int i = blockIdx.x;
  const int tt = (i >> 3) & 31;
  const int bh = (i & 7) + ((i >> 8) << 3);
  const int b = bh >> 4, h = bh & 15;
  const int tid = threadIdx.x, w = tid >> 6, l = tid & 63;
  __shared__ u16 Qs[64 * 64] __attribute__((aligned(16)));   // reused as P
  __shared__ u16 Ks[2][64 * 64] __attribute__((aligned(16)));
  __shared__ u16 Vs[2][64 * 64] __attribute__((aligned(16)));
  const u16* Qg = Qb + (size_t)bh * T_ * 64;
  const u16* Kg = Kb + (size_t)bh * T_ * 64;
  const u16* Vg = Vtg + (size_t)bh * 64 * T_;
  const float* lgp = lgc + (size_t)bh * T_;

  const int srow = l >> 3;
  const int kgrp = ((l & 7) ^ srow) * 8;
  const int ql = l & 15, g4 = l >> 4;

#pragma unroll
  for (int i2 = 0; i2 < 2; ++i2) {
    int c = w * 2 + i2;
    int row = c * 8 + srow;
    gload16(Qg + (size_t)(tt * 64 + row) * 64 + kgrp, (char*)Qs + c * 1024);
  }
  const float lgq = lgp[tt * 64 + w * 16 + ql];
  const float lgtop = lgp[tt * 64];
  __syncthreads();   // drains Q loads (vmcnt -> 0)

  short8 qf[2];
#pragma unroll
  for (int kk = 0; kk < 2; ++kk) {
    int row = w * 16 + ql;
    int slot = kk * 4 + g4;
    qf[kk] = *(const short8*)((const char*)Qs + row * 128 + ((slot ^ (row & 7)) << 4));
  }
  char* Pw = (char*)Qs + w * 2048;
  const int pswz = (ql & 7) << 4;

  f32x4 yacc[4] = {};

  {  // prologue: stage st=tt
    const int bs = tt & 1;
#pragma unroll
    for (int i2 = 0; i2 < 2; ++i2) {
      int c = w * 2 + i2, row = c * 8 + srow;
      gload16(Kg + (size_t)(tt * 64 + row) * 64 + kgrp, (char*)Ks[bs] + c * 1024);
      gload16(Vg + (size_t)row * T_ + tt * 64 + kgrp, (char*)Vs[bs] + c * 1024);
    }
  }

  for (int st = tt;; --st) {
    const int bs = st & 1;
    const bool last = (st == 0) || (lgtop - lgp[(st - 1) * 64 + 63] <= -20.f);
    if (!last) {   // prefetch st-1 into the other buffer
#pragma unroll
      for (int i2 = 0; i2 < 2; ++i2) {
        int c = w * 2 + i2, row = c * 8 + srow;
        gload16(Kg + (size_t)((st - 1) * 64 + row) * 64 + kgrp, (char*)Ks[bs ^ 1] + c * 1024);
        gload16(Vg + (size_t)row * T_ + (st - 1) * 64 + kgrp, (char*)Vs[bs ^ 1] + c * 1024);
      }
      asm volatile("s_waitcnt vmcnt(4)" ::: "memory");
    } else {
      asm volatile("s_waitcnt vmcnt(0)" ::: "memory");
    }
    __builtin_amdgcn_sched_barrier(0);
    __builtin_amdgcn_s_barrier();
    __builtin_amdgcn_sched_barrier(0);

    const float alpha = __expf(lgq - lgp[st * 64]);
    const bool diag = (st == tt);
    const char* Ksb = (const char*)Ks[bs];
    const char* Vsb = (const char*)Vs[bs];
#pragma unroll
    for (int n = 0; n < 4; ++n) {      // QK^T swapped: C[s][q]
      f32x4 s = {};
#pragma unroll
      for (int kk = 0; kk < 2; ++kk) {
        int row = n * 16 + ql;
        int slot = kk * 4 + g4;
        short8 kf = *(const short8*)(Ksb + row * 128 + ((slot ^ (row & 7)) << 4));
        s = __builtin_amdgcn_mfma_f32_16x16x32_bf16(kf, qf[kk], s, 0, 0, 0);
      }
      u16x4 pk;
#pragma unroll
      for (int r = 0; r < 4; ++r) {
        float pv = s[r] * alpha;
        if (diag && (n * 16 + g4 * 4 + r) > (w * 16 + ql)) pv = 0.f;
        pk[r] = f2bf(pv);
      }
      *(u16x4*)(Pw + ((ql * 128 + n * 32 + g4 * 8) ^ pswz)) = pk;
    }
#pragma unroll
    for (int kk = 0; kk < 2; ++kk) {   // PV: Y[q][dd]
      short8 pf = *(const short8*)(Pw + ((ql * 128 + kk * 64 + g4 * 16) ^ pswz));
#pragma unroll
      for (int n2 = 0; n2 < 4; ++n2) {
        int row = n2 * 16 + ql;
        int slot = kk * 4 + g4;
        short8 vf = *(const short8*)(Vsb + row * 128 + ((slot ^ (row & 7)) << 4));
        yacc[n2] = __builtin_amdgcn_mfma_f32_16x16x32_bf16(pf, vf, yacc[n2], 0, 0, 0);
      }
    }
    if (last) break;
    __builtin_amdgcn_s_barrier();   // all waves done reading buf bs
  }

#pragma unroll
  for (int n2 = 0; n2 < 4; ++n2)
#pragma unroll
    for (int r = 0; r < 4; ++r) {
      size_t row = (size_t)(b * T_) + tt * 64 + w * 16 + g4 * 4 + r;
      Y[row * INNER_ + h * 64 + n2 * 16 + ql] = f2bf(yacc[n2][r]);
    }
}

// ---------------------------------------------------------------------------
extern "C" void kernel_launch(void* const* d_in, const int* in_sizes, int n_in,
                              void* d_out, int out_size, void* d_ws, size_t ws_size,
                              hipStream_t stream) {
  const float* x        = (const float*)d_in[0];
  const float* W_qkv    = (const float*)d_in[1];
  const float* W_out    = (const float*)d_in[2];
  const float* W_dt     = (const float*)d_in[3];
  const float* b_dt     = (const float*)d_in[4];
  const float* W_gsp    = (const float*)d_in[5];
  const float* b_gsp    = (const float*)d_in[6];
  const float* inv_freq = (const float*)d_in[7];
  float* out = (float*)d_out;

  const int M = B_ * T_;  // 4096
  char* p = (char*)d_ws;
  auto alloc = [&](size_t bytes) {
    char* r = p; p += (bytes + 255) & ~(size_t)255; return r;
  };
  u16*    xb    = (u16*)alloc((size_t)M * D_ * 2);             // 8 MB
  u16*    Wcombt= (u16*)alloc((size_t)NC_ * D_ * 2);           // 8 MB
  u16*    Woutt = (u16*)alloc((size_t)D_ * INNER_ * 2);        // 2 MB
  u16*    Wdtb  = (u16*)alloc((size_t)H_ * D_ * 2);            // 32 KB
  u16*    Cqkvp = (u16*)alloc((size_t)M * NC_ * 2);            // 32 MB
  u16*    Qb    = (u16*)alloc((size_t)B_ * H_ * T_ * 64 * 2);  // 8 MB
  u16*    Kb    = (u16*)alloc((size_t)B_ * H_ * T_ * 64 * 2);
  u16*    Vb    = (u16*)alloc((size_t)B_ * H_ * T_ * 64 * 2);
  float*  gam   = (float*)alloc((size_t)M * H_ * 4);           // 256 KB
  float*  lg    = (float*)alloc((size_t)B_ * H_ * T_ * 4);
  float*  lgc   = (float*)alloc((size_t)B_ * H_ * T_ * 4);
  float2* tab   = (float2*)alloc((size_t)T_ * 32 * 8);         // 512 KB
  // after pointwise, Cqkvp is dead -> alias attention buffers into it
  u16*    Vtg   = Cqkvp;                                       // 8 MB
  u16*    Yb    = Cqkvp + (size_t)4 * 1024 * 1024;             // 8 MB

  // fused prep (casts, transposes, rope table)
  prep_kernel<<<2624, 256, 0, stream>>>(x, W_qkv, W_gsp, W_out, W_dt, inv_freq,
                                        xb, Wcombt, Woutt, Wdtb, tab);
  // dt matvec
  gamma_kernel<<<M / 4, 256, 0, stream>>>(xb, Wdtb, b_dt, gam);
  // combined projection GEMM: [q|k|v|praw] = x @ [W_qkv|W_gsp]  (N=4096)
  gemm_big<<<256, 512, 0, stream>>>(xb, Wcombt, Cqkvp);

  pointwise_kernel<<<M / 4, 256, 0, stream>>>(Cqkvp, gam, b_gsp, tab,
                                              Qb, Kb, Vb, lg);
  scan_kernel<<<B_ * H_, 256, 0, stream>>>(lg, lgc);
  kv_prep_kernel<<<dim3(T_ / 64, B_ * H_), 256, 0, stream>>>(Vb, lgc, Vtg);

  attn_mfma<<<1024, 256, 0, stream>>>(Qb, Kb, Vtg, lgc, Yb);

  // out = Y @ W_out  (fp32 out)
  gemm_bt<false><<<256, 256, 0, stream>>>(Yb, Woutt, out, M, D_, INNER_);
}